// Round 12
// baseline (81.452 us; speedup 1.0000x reference)
//
#include <hip/hip_runtime.h>
#include <hip/hip_bf16.h>
#include <stdint.h>
#include <stddef.h>

// ---------------------------------------------------------------------------
// SSRupsampling3 == two small GEMMs:
//   T  = f(Wbig[384x512] @ x)     (relu+bias rows 128..383)
//   out= W2[512x384] @ T          (+ pixel-shuffle scatter)
// R12 = R9 fused (best known, ~39.4us steady) + rewritten prep:
// prep was L2-BW-bound on redundant reads (~163 MB -> ~5.4us). New prep uses
// 4x4 register tiling (256B/elem instead of 1KB/elem) in two kernels
// (Mrows -> W2 is a cross-block dep). Full fp32 precision kept.
// ---------------------------------------------------------------------------

typedef __attribute__((ext_vector_type(8))) __bf16 bf16x8;
typedef __attribute__((ext_vector_type(4))) float  f32x4;
typedef __attribute__((ext_vector_type(2))) float  f32x2;
typedef __attribute__((ext_vector_type(4))) unsigned int u32x4;
typedef __attribute__((ext_vector_type(2))) unsigned int u32x2;

#define BAR() asm volatile("s_waitcnt lgkmcnt(0)\n\ts_barrier" ::: "memory")

// A-fragment layout for mfma_f32_16x16x32_bf16 (verified R1-R11):
//   lane l holds A[row = mfrag*16 + (l&15)][k = gks*32 + (l>>4)*8 + j]
// Element index: frag[((gks*NMF + mfrag)<<9) + ((lrow + 16*lsub)<<3) + jj]
// with gks=c>>5, lsub=(c>>3)&3, jj=c&7, mfrag=r>>4, lrow=r&15.

// ---------------- prep1: Wa (tiled) + center taps + Mrows (tiled) -----------
// blocks 0..15 : Wa = w_ch[:, :128] @ w_1x1 -> Wf rows 0..127   (4x4/thread)
// blocks 16..31: Mrows[512][128] (4x4/thread)
// blocks 32..63: center taps -> Wf rows 128..383 (16 c/thread, vector stores)

__global__ __launch_bounds__(256) void prep1_k(
    const float* __restrict__ w_ch, const float* __restrict__ w_1x1,
    const float* __restrict__ w_lr, const float* __restrict__ w_du,
    const float* __restrict__ w_H,  const float* __restrict__ w_w,
    __bf16* __restrict__ Wf, float* __restrict__ Mrows)
{
  const int bid = blockIdx.x, tid = threadIdx.x;
  char* Wfb = (char*)Wf;

  if (bid < 16) {
    // Wa: 32 rgroups x 128 cgroups (4x4 each)
    int tt = bid * 256 + tid;
    int r0 = (tt >> 7) * 4, c0 = (tt & 127) * 4;
    float acc[4][4] = {};
    #pragma unroll 4
    for (int j = 0; j < 128; j += 4) {
      f32x4 a[4], b[4];
      #pragma unroll
      for (int i = 0; i < 4; ++i)
        a[i] = *(const f32x4*)(w_ch + (size_t)(r0 + i) * 384 + j);
      #pragma unroll
      for (int q = 0; q < 4; ++q)
        b[q] = *(const f32x4*)(w_1x1 + (size_t)(j + q) * 512 + c0);
      #pragma unroll
      for (int i = 0; i < 4; ++i)
        #pragma unroll
        for (int q = 0; q < 4; ++q) {
          acc[i][0] += a[i][q] * b[q][0];
          acc[i][1] += a[i][q] * b[q][1];
          acc[i][2] += a[i][q] * b[q][2];
          acc[i][3] += a[i][q] * b[q][3];
        }
    }
    const int gks = c0 >> 5, lsub = (c0 >> 3) & 3, jj0 = c0 & 7;
    #pragma unroll
    for (int i = 0; i < 4; ++i) {
      int r = r0 + i;
      union { __bf16 b[4]; u32x2 u; } wd;
      #pragma unroll
      for (int q = 0; q < 4; ++q) wd.b[q] = (__bf16)acc[i][q];
      *(u32x2*)(Wfb + (((gks * 24 + (r >> 4)) << 10) +
                       (((r & 15) + 16 * lsub) << 4) + jj0 * 2)) = wd.u;
    }
  } else if (bid < 32) {
    // Mrows: 128 rgroups x 32 kgroups (4x4 each)
    int tt = (bid - 16) * 256 + tid;
    int r0 = (tt >> 5) * 4, k0 = (tt & 31) * 4;
    const int beta = r0 >> 8;
    const float* whp[4];
    #pragma unroll
    for (int i = 0; i < 4; ++i) {
      int rr = r0 + i;
      whp[i] = w_H + (size_t)((rr & 1) * 128 + ((rr >> 1) & 127)) * 128;
    }
    const float* wwb = w_w + (size_t)beta * 16384 + k0;
    float acc[4][4] = {};
    #pragma unroll 4
    for (int t = 0; t < 128; t += 4) {
      f32x4 h[4], w[4];
      #pragma unroll
      for (int i = 0; i < 4; ++i) h[i] = *(const f32x4*)(whp[i] + t);
      #pragma unroll
      for (int q = 0; q < 4; ++q) w[q] = *(const f32x4*)(wwb + (size_t)(t + q) * 128);
      #pragma unroll
      for (int i = 0; i < 4; ++i)
        #pragma unroll
        for (int q = 0; q < 4; ++q) {
          acc[i][0] += h[i][q] * w[q][0];
          acc[i][1] += h[i][q] * w[q][1];
          acc[i][2] += h[i][q] * w[q][2];
          acc[i][3] += h[i][q] * w[q][3];
        }
    }
    #pragma unroll
    for (int i = 0; i < 4; ++i) {
      f32x4 o; o.x = acc[i][0]; o.y = acc[i][1]; o.z = acc[i][2]; o.w = acc[i][3];
      *(f32x4*)(Mrows + (size_t)(r0 + i) * 128 + k0) = o;
    }
  } else {
    // center taps: rr 0..255 (row 128+rr), 16 consecutive c per thread
    int tt = (bid - 32) * 256 + tid;        // 8192 threads
    int rr = tt >> 5, c0 = (tt & 31) * 16;
    int r = 128 + rr;
    const float* src = (rr < 128) ? (w_lr + (size_t)rr * 1536 + 1)
                                  : (w_du + (size_t)(rr - 128) * 1536 + 1);
    const int mfrag = r >> 4, lrow = r & 15;
    #pragma unroll
    for (int g = 0; g < 2; ++g) {           // two groups of 8 c
      int cg0 = c0 + g * 8;
      int gks = cg0 >> 5, lsub = (cg0 >> 3) & 3;
      union { __bf16 b[8]; u32x4 u; } wd;
      #pragma unroll
      for (int q = 0; q < 8; ++q) wd.b[q] = (__bf16)src[(cg0 + q) * 3];
      *(u32x4*)(Wfb + (((gks * 24 + mfrag) << 10) +
                       ((lrow + 16 * lsub) << 4))) = wd.u;
    }
  }
}

// ---------------- prep2: W2 fragments from Mrows + w_ch ---------------------
// blocks 0..31 : cols 128..383 = Mrows @ w_ch[:,128:384]  (4x4/thread)
// blocks 32..63: cols 0..127 copy of Mrows (8 c/thread, vector store)

__global__ __launch_bounds__(256) void prep2_k(
    const float* __restrict__ Mrows, const float* __restrict__ w_ch,
    __bf16* __restrict__ W2f)
{
  const int bid = blockIdx.x, tid = threadIdx.x;
  char* W2b = (char*)W2f;

  if (bid < 32) {
    int tt = bid * 256 + tid;               // 8192 tasks
    int r0 = (tt >> 6) * 4, c0 = 128 + (tt & 63) * 4;
    float acc[4][4] = {};
    #pragma unroll 4
    for (int k = 0; k < 128; k += 4) {
      f32x4 m[4], w[4];
      #pragma unroll
      for (int i = 0; i < 4; ++i)
        m[i] = *(const f32x4*)(Mrows + (size_t)(r0 + i) * 128 + k);
      #pragma unroll
      for (int q = 0; q < 4; ++q)
        w[q] = *(const f32x4*)(w_ch + (size_t)(k + q) * 384 + c0);
      #pragma unroll
      for (int i = 0; i < 4; ++i)
        #pragma unroll
        for (int q = 0; q < 4; ++q) {
          acc[i][0] += m[i][q] * w[q][0];
          acc[i][1] += m[i][q] * w[q][1];
          acc[i][2] += m[i][q] * w[q][2];
          acc[i][3] += m[i][q] * w[q][3];
        }
    }
    const int gks = c0 >> 5, lsub = (c0 >> 3) & 3, jj0 = c0 & 7;
    #pragma unroll
    for (int i = 0; i < 4; ++i) {
      int r = r0 + i;
      union { __bf16 b[4]; u32x2 u; } wd;
      #pragma unroll
      for (int q = 0; q < 4; ++q) wd.b[q] = (__bf16)acc[i][q];
      *(u32x2*)(W2b + (((gks * 32 + (r >> 4)) << 10) +
                       (((r & 15) + 16 * lsub) << 4) + jj0 * 2)) = wd.u;
    }
  } else {
    int tt = (bid - 32) * 256 + tid;        // 8192 threads
    int r = tt >> 4, c0 = (tt & 15) * 8;
    f32x4 m0 = *(const f32x4*)(Mrows + (size_t)r * 128 + c0);
    f32x4 m1 = *(const f32x4*)(Mrows + (size_t)r * 128 + c0 + 4);
    int gks = c0 >> 5, lsub = (c0 >> 3) & 3;
    union { __bf16 b[8]; u32x4 u; } wd;
    wd.b[0] = (__bf16)m0.x; wd.b[1] = (__bf16)m0.y;
    wd.b[2] = (__bf16)m0.z; wd.b[3] = (__bf16)m0.w;
    wd.b[4] = (__bf16)m1.x; wd.b[5] = (__bf16)m1.y;
    wd.b[6] = (__bf16)m1.z; wd.b[7] = (__bf16)m1.w;
    *(u32x4*)(W2b + (((gks * 32 + (r >> 4)) << 10) +
                     (((r & 15) + 16 * lsub) << 4))) = wd.u;
  }
}

// ---------------- fused kernel (R9 verbatim, best known) --------------------

__device__ __forceinline__ int swzB(int px) {
  return (((px & 7) ^ ((px >> 3) & 7)) << 4);
}

__global__ __launch_bounds__(256, 2) void fused_k(
    const float* __restrict__ x, const __bf16* __restrict__ Wf,
    const __bf16* __restrict__ W2f,
    const float* __restrict__ b_lr, const float* __restrict__ b_du,
    float* __restrict__ out)
{
  __shared__ __align__(16) char smem[49152 + 16384];
  char* Tlds = smem;                 // 64 px * 768 B (384 k bf16), swizzled
  char* buf0 = smem + 49152;         // 64 px * 128 B
  char* buf1 = smem + 49152 + 8192;

  const int tid  = threadIdx.x;
  const int lane = tid & 63;
  const int wv   = tid >> 6;          // 0..3
  const int l15  = lane & 15, lg = lane >> 4;

  const int p0      = blockIdx.x * 64;
  const int img     = p0 >> 12;
  const int pixbase = p0 & 4095;
  const float* xb   = x + (size_t)img * (512 * 4096) + pixbase;
  const char* Wfb   = (const char*)Wf;
  const char* W2b   = (const char*)W2f;

  const int sp4 = (tid & 15) * 4;     // pixel quad
  const int sk4 = (tid >> 4) * 4;     // k quad, 0..60

  f32x4 ldv[4];
  auto issueS = [&](int kt) {
    #pragma unroll
    for (int j = 0; j < 4; ++j)
      ldv[j] = *(const f32x4*)(xb + (size_t)(kt * 64 + sk4 + j) * 4096 + sp4);
  };
  auto writeS = [&](char* bw) {
    #pragma unroll
    for (int pi = 0; pi < 4; ++pi) {
      int px = sp4 + pi;
      union { __bf16 b[4]; u32x2 u; } wd;
      wd.b[0] = (__bf16)ldv[0][pi];
      wd.b[1] = (__bf16)ldv[1][pi];
      wd.b[2] = (__bf16)ldv[2][pi];
      wd.b[3] = (__bf16)ldv[3][pi];
      *(u32x2*)(bw + px * 128 + ((sk4 * 2) ^ swzB(px))) = wd.u;
    }
  };

  // ---------------- phase 1: T = f(Wbig @ x_tile) ----------------
  f32x4 acc1[6][4] = {};

  auto compute1 = [&](int kt, const char* bbuf) {
    #pragma unroll
    for (int ks = 0; ks < 2; ++ks) {
      bf16x8 af[6];
      #pragma unroll
      for (int i = 0; i < 6; ++i)
        af[i] = *(const bf16x8*)(Wfb +
            (((kt * 2 + ks) * 24 + wv * 6 + i) << 10) + lane * 16);
      bf16x8 bfr[4];
      #pragma unroll
      for (int j = 0; j < 4; ++j) {
        int rb = j * 16 + l15;
        bfr[j] = *(const bf16x8*)(bbuf + rb * 128 +
                                  ((ks * 64 + lg * 16) ^ swzB(rb)));
      }
      __builtin_amdgcn_s_setprio(1);
      #pragma unroll
      for (int i = 0; i < 6; ++i)
        #pragma unroll
        for (int j = 0; j < 4; ++j)
          acc1[i][j] = __builtin_amdgcn_mfma_f32_16x16x32_bf16(
              af[i], bfr[j], acc1[i][j], 0, 0, 0);
      __builtin_amdgcn_s_setprio(0);
    }
  };

  issueS(0);
  writeS(buf0);
  issueS(1);
  BAR();

  #pragma unroll 1
  for (int kt = 0; kt < 8; ++kt) {
    const char* bcur = (kt & 1) ? buf1 : buf0;
    char* bnext      = (kt & 1) ? buf0 : buf1;
    compute1(kt, bcur);
    if (kt < 7) {
      writeS(bnext);
      if (kt < 6) issueS(kt + 2);
      BAR();
    }
  }

  // epilogue 1: bias+relu rows>=128, write T' to Tlds [px][384] bf16
  #pragma unroll
  for (int i = 0; i < 6; ++i) {
    int m0 = wv * 96 + i * 16 + lg * 4;
    bool rl = (m0 >= 128);
    const float* bp = (m0 >= 256) ? (b_du + (m0 - 256)) : (b_lr + (m0 - 128));
    float b0 = 0.f, b1 = 0.f, b2 = 0.f, b3 = 0.f;
    if (rl) { b0 = bp[0]; b1 = bp[1]; b2 = bp[2]; b3 = bp[3]; }
    #pragma unroll
    for (int j = 0; j < 4; ++j) {
      int p = j * 16 + l15;
      union { __bf16 b[4]; u32x2 u; } wd;
      float v0 = acc1[i][j][0], v1 = acc1[i][j][1];
      float v2 = acc1[i][j][2], v3 = acc1[i][j][3];
      if (rl) {
        v0 = fmaxf(v0 + b0, 0.f); v1 = fmaxf(v1 + b1, 0.f);
        v2 = fmaxf(v2 + b2, 0.f); v3 = fmaxf(v3 + b3, 0.f);
      }
      wd.b[0] = (__bf16)v0; wd.b[1] = (__bf16)v1;
      wd.b[2] = (__bf16)v2; wd.b[3] = (__bf16)v3;
      *(u32x2*)(Tlds + p * 768 + ((m0 * 2) ^ ((p & 7) << 4))) = wd.u;
    }
  }
  BAR();

  // ---------------- phase 2: out = W2 @ T (barrier-free K loop) -------------
  f32x4 acc2[8][4] = {};
  bf16x8 afA[8], afB[8];
  #pragma unroll
  for (int i = 0; i < 8; ++i)
    afA[i] = *(const bf16x8*)(W2b + ((0 * 32 + wv * 8 + i) << 10) + lane * 16);

  #pragma unroll 1
  for (int g2 = 0; g2 < 6; ++g2) {
    int gA = 2 * g2, gB = 2 * g2 + 1;
    #pragma unroll
    for (int i = 0; i < 8; ++i)
      afB[i] = *(const bf16x8*)(W2b + ((gB * 32 + wv * 8 + i) << 10) + lane * 16);
    {
      bf16x8 bfr[4];
      #pragma unroll
      for (int j = 0; j < 4; ++j) {
        int rb = j * 16 + l15;
        bfr[j] = *(const bf16x8*)(Tlds + rb * 768 +
                                  ((gA * 64 + lg * 16) ^ ((rb & 7) << 4)));
      }
      __builtin_amdgcn_s_setprio(1);
      #pragma unroll
      for (int i = 0; i < 8; ++i)
        #pragma unroll
        for (int j = 0; j < 4; ++j)
          acc2[i][j] = __builtin_amdgcn_mfma_f32_16x16x32_bf16(
              afA[i], bfr[j], acc2[i][j], 0, 0, 0);
      __builtin_amdgcn_s_setprio(0);
    }
    if (g2 < 5) {
      #pragma unroll
      for (int i = 0; i < 8; ++i)
        afA[i] = *(const bf16x8*)(W2b + (((gA + 2) * 32 + wv * 8 + i) << 10) + lane * 16);
    }
    {
      bf16x8 bfr[4];
      #pragma unroll
      for (int j = 0; j < 4; ++j) {
        int rb = j * 16 + l15;
        bfr[j] = *(const bf16x8*)(Tlds + rb * 768 +
                                  ((gB * 64 + lg * 16) ^ ((rb & 7) << 4)));
      }
      __builtin_amdgcn_s_setprio(1);
      #pragma unroll
      for (int i = 0; i < 8; ++i)
        #pragma unroll
        for (int j = 0; j < 4; ++j)
          acc2[i][j] = __builtin_amdgcn_mfma_f32_16x16x32_bf16(
              afB[i], bfr[j], acc2[i][j], 0, 0, 0);
      __builtin_amdgcn_s_setprio(0);
    }
  }

  // epilogue 2: pixel-shuffle scatter. row r = beta*256 + irow*2 + gamma.
  #pragma unroll
  for (int i = 0; i < 8; ++i) {
    int r = wv * 128 + i * 16 + lg * 4;   // even
    int beta = r >> 8;
    int irow = (r >> 1) & 127;
    #pragma unroll
    for (int j = 0; j < 4; ++j) {
      int pp = pixbase + j * 16 + l15;
      int h = pp >> 6, w = pp & 63;
      size_t o0 = ((((size_t)img * 128 + irow) * 128) + (2 * h + beta)) * 128
                  + 2 * w;
      f32x2 lo; lo.x = acc2[i][j][0]; lo.y = acc2[i][j][1];
      f32x2 hi; hi.x = acc2[i][j][2]; hi.y = acc2[i][j][3];
      *(f32x2*)(out + o0)         = lo;   // channel irow
      *(f32x2*)(out + o0 + 16384) = hi;   // channel irow+1
    }
  }
}

// ---------------- launcher ---------------------------------------------------

extern "C" void kernel_launch(void* const* d_in, const int* in_sizes, int n_in,
                              void* d_out, int out_size, void* d_ws, size_t ws_size,
                              hipStream_t stream) {
  const float* x     = (const float*)d_in[0];
  const float* w_du  = (const float*)d_in[1];
  const float* b_du  = (const float*)d_in[2];
  const float* w_lr  = (const float*)d_in[3];
  const float* b_lr  = (const float*)d_in[4];
  const float* w_1x1 = (const float*)d_in[5];
  const float* w_ch  = (const float*)d_in[6];
  const float* w_w   = (const float*)d_in[7];
  const float* w_H   = (const float*)d_in[8];
  float* out = (float*)d_out;

  char* ws = (char*)d_ws;
  __bf16* Wf    = (__bf16*)(ws + 0);        // 16*24*1024 = 393216
  __bf16* W2f   = (__bf16*)(ws + 393216);   // 12*32*1024 = 393216
  float*  Mrows = (float*) (ws + 786432);   // 512*128*4  = 262144
  if (ws_size < (size_t)1048576) return;

  prep1_k<<<64, 256, 0, stream>>>(w_ch, w_1x1, w_lr, w_du, w_H, w_w, Wf, Mrows);
  prep2_k<<<64, 256, 0, stream>>>(Mrows, w_ch, W2f);
  fused_k<<<512, 256, 0, stream>>>(x, Wf, W2f, b_lr, b_du, out);
}